// Round 5
// baseline (234.242 us; speedup 1.0000x reference)
//
#include <hip/hip_runtime.h>
#include <hip/hip_bf16.h>

typedef __bf16 bf16_t;
typedef bf16_t bf16x8 __attribute__((ext_vector_type(8)));
typedef float f32x4 __attribute__((ext_vector_type(4)));
typedef float f32x16 __attribute__((ext_vector_type(16)));
typedef unsigned short u16;
typedef unsigned int u32;

#define B_    2
#define S_    2048
#define HID   2048
#define NQKV  3072          // (16 + 2*4) * 128
#define HQ_   16
#define HKV_  4
#define D_    128
// D^-0.5 * log2(e): folded into Q so softmax runs in exp2 domain
#define QSCALE_ 0.12751879526600565f

__device__ __forceinline__ u16 f2b(float f) {
    __hip_bfloat16 h = __float2bfloat16(f);
    return *reinterpret_cast<u16*>(&h);
}

// ---------------------------------------------------------------- f32 -> bf16
__global__ __launch_bounds__(256) void cvt_f32_bf16(const float* __restrict__ in,
                                                    u16* __restrict__ out, int n4) {
    int i = blockIdx.x * 256 + threadIdx.x;
    if (i >= n4) return;
    float4 v = reinterpret_cast<const float4*>(in)[i];
    ushort4 o;
    o.x = f2b(v.x); o.y = f2b(v.y); o.z = f2b(v.z); o.w = f2b(v.w);
    reinterpret_cast<ushort4*>(out)[i] = o;
}

// ---------------------------------------------------------------- GEMM 256x256, BK=64, 8 waves (2Mx4N)
// Template-style phases: {pre-barrier ds_read subtile || stage next half-tile,
// barrier, setprio+16 MFMA, barrier}. vmcnt(0) after phase-4 MFMA (hidden).
// LDS 128KB dbuf, XOR swizzle (byte ^= (row&7)<<4) on stage-src + read side.
__global__ __launch_bounds__(512, 1) void gemm256_bt(const u16* __restrict__ A,
                                                     const u16* __restrict__ Bm,
                                                     float* __restrict__ C,
                                                     int M, int N, int K) {
    extern __shared__ __align__(16) char smem[];
    u16* Asm = (u16*)smem;                 // [2][256*64]
    u16* Bsm = (u16*)smem + 32768;         // [2][256*64]

    const int tid  = threadIdx.x;
    const int lane = tid & 63;
    const int wid  = tid >> 6;
    const int wr = wid >> 2, wc = wid & 3;          // wave -> (128M x 64N) tile
    const int lrow = lane & 15, lgrp = lane >> 4;
    const int swz  = (lrow & 7) << 4;
    const int m0 = blockIdx.x * 256, n0 = blockIdx.y * 256;

    const int stRow = tid >> 3;                               // 0..63
    const int stCol = ((((tid & 7) * 16) ^ ((stRow & 7) << 4)) >> 1);

    const u16* aBase = A  + (size_t)(m0 + stRow) * K + stCol;
    const u16* bBase = Bm + (size_t)(n0 + stRow) * K + stCol;

    auto glds = [&](const u16* g, u16* l) {
        __builtin_amdgcn_global_load_lds(
            (const __attribute__((address_space(1))) void*)g,
            (__attribute__((address_space(3))) void*)l, 16, 0, 0);
    };
    auto stageA = [&](int buf, int h, int k0) {
        const u16* g = aBase + (size_t)(128 * h) * K + k0;
        u16* d = Asm + buf * 16384 + (1024 * h + tid) * 8;
        glds(g, d);
        glds(g + (size_t)64 * K, d + 512 * 8);
    };
    auto stageB = [&](int buf, int h, int k0) {
        const u16* g = bBase + (size_t)(128 * h) * K + k0;
        u16* d = Bsm + buf * 16384 + (1024 * h + tid) * 8;
        glds(g, d);
        glds(g + (size_t)64 * K, d + 512 * 8);
    };

    f32x4 acc[8][4] = {};
    const int KT = K >> 6;

    // prologue: stage tile 0 fully, drain, barrier
    stageA(0, 0, 0); stageA(0, 1, 0); stageB(0, 0, 0); stageB(0, 1, 0);
    asm volatile("s_waitcnt vmcnt(0)" ::: "memory");
    __builtin_amdgcn_s_barrier();

    for (int x = 0; x < KT; ++x) {
        const int cur = x & 1;
        const int kn  = (x + 1) << 6;
        const bool pf = (x + 1 < KT);
        const char* aT = (const char*)(Asm + cur * 16384);
        const char* bT = (const char*)(Bsm + cur * 16384);

        auto ldA = [&](int mi, int ks) -> bf16x8 {
            int row = wr * 128 + mi * 16 + lrow;
            return *(const bf16x8*)(aT + row * 128 + ((ks * 64 + lgrp * 16) ^ swz));
        };
        auto ldB = [&](int ni, int ks) -> bf16x8 {
            int row = wc * 64 + ni * 16 + lrow;
            return *(const bf16x8*)(bT + row * 128 + ((ks * 64 + lgrp * 16) ^ swz));
        };

        bf16x8 a[4][2], b[2][2], b2[2][2];

        // ---- phase 1: pre-read A-rows0 + B-cols0; stage A-half0(next)
        #pragma unroll
        for (int mi = 0; mi < 4; ++mi) { a[mi][0] = ldA(mi, 0); a[mi][1] = ldA(mi, 1); }
        #pragma unroll
        for (int ni = 0; ni < 2; ++ni) { b[ni][0] = ldB(ni, 0); b[ni][1] = ldB(ni, 1); }
        if (pf) stageA(cur ^ 1, 0, kn);
        __builtin_amdgcn_s_barrier();
        __builtin_amdgcn_s_setprio(1);
        #pragma unroll
        for (int mi = 0; mi < 4; ++mi)
            #pragma unroll
            for (int ni = 0; ni < 2; ++ni) {
                acc[mi][ni] = __builtin_amdgcn_mfma_f32_16x16x32_bf16(a[mi][0], b[ni][0], acc[mi][ni], 0, 0, 0);
                acc[mi][ni] = __builtin_amdgcn_mfma_f32_16x16x32_bf16(a[mi][1], b[ni][1], acc[mi][ni], 0, 0, 0);
            }
        __builtin_amdgcn_s_setprio(0);
        __builtin_amdgcn_s_barrier();

        // ---- phase 2: pre-read B-cols1; stage A-half1(next); reuse a
        #pragma unroll
        for (int ni = 0; ni < 2; ++ni) { b2[ni][0] = ldB(ni + 2, 0); b2[ni][1] = ldB(ni + 2, 1); }
        if (pf) stageA(cur ^ 1, 1, kn);
        __builtin_amdgcn_s_barrier();
        __builtin_amdgcn_s_setprio(1);
        #pragma unroll
        for (int mi = 0; mi < 4; ++mi)
            #pragma unroll
            for (int ni = 0; ni < 2; ++ni) {
                acc[mi][ni + 2] = __builtin_amdgcn_mfma_f32_16x16x32_bf16(a[mi][0], b2[ni][0], acc[mi][ni + 2], 0, 0, 0);
                acc[mi][ni + 2] = __builtin_amdgcn_mfma_f32_16x16x32_bf16(a[mi][1], b2[ni][1], acc[mi][ni + 2], 0, 0, 0);
            }
        __builtin_amdgcn_s_setprio(0);
        __builtin_amdgcn_s_barrier();

        // ---- phase 3: pre-read A-rows1 (overwrite a); stage B-half0(next)
        #pragma unroll
        for (int mi = 0; mi < 4; ++mi) { a[mi][0] = ldA(mi + 4, 0); a[mi][1] = ldA(mi + 4, 1); }
        if (pf) stageB(cur ^ 1, 0, kn);
        __builtin_amdgcn_s_barrier();
        __builtin_amdgcn_s_setprio(1);
        #pragma unroll
        for (int mi = 0; mi < 4; ++mi)
            #pragma unroll
            for (int ni = 0; ni < 2; ++ni) {
                acc[mi + 4][ni + 2] = __builtin_amdgcn_mfma_f32_16x16x32_bf16(a[mi][0], b2[ni][0], acc[mi + 4][ni + 2], 0, 0, 0);
                acc[mi + 4][ni + 2] = __builtin_amdgcn_mfma_f32_16x16x32_bf16(a[mi][1], b2[ni][1], acc[mi + 4][ni + 2], 0, 0, 0);
            }
        __builtin_amdgcn_s_setprio(0);
        __builtin_amdgcn_s_barrier();

        // ---- phase 4: pre-read B-cols0 (overwrite b); stage B-half1(next);
        //      vmcnt(0) AFTER MFMA (hidden) so next-iter pre-reads are safe
        #pragma unroll
        for (int ni = 0; ni < 2; ++ni) { b[ni][0] = ldB(ni, 0); b[ni][1] = ldB(ni, 1); }
        if (pf) stageB(cur ^ 1, 1, kn);
        __builtin_amdgcn_s_barrier();
        __builtin_amdgcn_s_setprio(1);
        #pragma unroll
        for (int mi = 0; mi < 4; ++mi)
            #pragma unroll
            for (int ni = 0; ni < 2; ++ni) {
                acc[mi + 4][ni] = __builtin_amdgcn_mfma_f32_16x16x32_bf16(a[mi][0], b[ni][0], acc[mi + 4][ni], 0, 0, 0);
                acc[mi + 4][ni] = __builtin_amdgcn_mfma_f32_16x16x32_bf16(a[mi][1], b[ni][1], acc[mi + 4][ni], 0, 0, 0);
            }
        __builtin_amdgcn_s_setprio(0);
        asm volatile("s_waitcnt vmcnt(0)" ::: "memory");
        __builtin_amdgcn_s_barrier();
    }

    // ---- epilogue: C write (f32)
    #pragma unroll
    for (int mi = 0; mi < 8; ++mi)
        #pragma unroll
        for (int ni = 0; ni < 4; ++ni) {
            int r = m0 + wr * 128 + mi * 16 + lgrp * 4;
            int c = n0 + wc * 64 + ni * 16 + lrow;
            float* p = C + (size_t)r * N + c;
            #pragma unroll
            for (int i = 0; i < 4; ++i) p[(size_t)i * N] = acc[mi][ni][i];
        }
}

// ---------------------------------------------------------------- RoPE (interleaved) + RMSNorm + split/relayout
__global__ __launch_bounds__(256) void rope_norm_split(const float* __restrict__ qkv,
                                                       const float* __restrict__ cosb,
                                                       const float* __restrict__ sinb,
                                                       const float* __restrict__ nw,
                                                       u16* __restrict__ qb,
                                                       u16* __restrict__ kb,
                                                       u16* __restrict__ vb) {
    const int row  = blockIdx.x;          // b*S + s
    const int b    = row >> 11;
    const int s    = row & 2047;
    const int wave = threadIdx.x >> 6;
    const int lane = threadIdx.x & 63;
    const float* base = qkv + (size_t)row * NQKV;

    const float c0 = cosb[s * 128 + lane];
    const float c1 = cosb[s * 128 + 64 + lane];
    const float s0 = sinb[s * 128 + lane];
    const float s1 = sinb[s * 128 + 64 + lane];
    const float w0 = nw[2 * lane];
    const float w1 = nw[2 * lane + 1];

    for (int h = wave; h < HQ_ + HKV_; h += 4) {
        float2 x = *(const float2*)(base + h * 128 + 2 * lane);
        float y0 = x.x * c0 - x.y * s0;
        float y1 = x.y * c1 + x.x * s1;
        float ss = y0 * y0 + y1 * y1;
        #pragma unroll
        for (int off = 32; off; off >>= 1) ss += __shfl_xor(ss, off);
        float r = rsqrtf(ss * (1.0f / 128.0f) + 1e-6f);
        float o0 = y0 * r * w0, o1 = y1 * r * w1;
        if (h < HQ_) {
            u32 pack = (u32)f2b(o0 * QSCALE_) | ((u32)f2b(o1 * QSCALE_) << 16);
            *(u32*)(qb + ((size_t)(b * HQ_ + h) * S_ + s) * D_ + 2 * lane) = pack;
        } else {
            u32 pack = (u32)f2b(o0) | ((u32)f2b(o1) << 16);
            *(u32*)(kb + ((size_t)(b * HKV_ + (h - HQ_)) * S_ + s) * D_ + 2 * lane) = pack;
        }
    }
    {
        int h = wave;
        float2 x = *(const float2*)(base + (HQ_ + HKV_) * 128 + h * 128 + 2 * lane);
        u32 pack = (u32)f2b(x.x) | ((u32)f2b(x.y) << 16);
        *(u32*)(vb + ((size_t)(b * HKV_ + h) * S_ + s) * D_ + 2 * lane) = pack;
    }
}

// ---------------------------------------------------------------- V transpose: (B,HKV,S,D) -> (B,HKV,D,S)
__global__ __launch_bounds__(256) void transpose_v(const u16* __restrict__ vb,
                                                   u16* __restrict__ vtb) {
    __shared__ u16 t[64][72];
    const int s0 = blockIdx.x * 64, d0 = blockIdx.y * 64, bh = blockIdx.z;
    const u16* src = vb  + (size_t)bh * S_ * D_;
    u16*       dst = vtb + (size_t)bh * D_ * S_;
    const int tid = threadIdx.x;

    {
        int r = tid >> 3, c8 = (tid & 7) * 8;
        #pragma unroll
        for (int p = 0; p < 2; p++) {
            int rr = r + p * 32;
            *(uint4*)&t[rr][c8] = *(const uint4*)(src + (size_t)(s0 + rr) * D_ + d0 + c8);
        }
    }
    __syncthreads();
    {
        int dd = tid & 63;
        int sb = (tid >> 6) * 8;
        #pragma unroll
        for (int p = 0; p < 2; p++) {
            int ss8 = sb + p * 32;
            union { u16 u[8]; uint4 v; } pk;
            #pragma unroll
            for (int j = 0; j < 8; j++) pk.u[j] = t[ss8 + j][dd];
            *(uint4*)(dst + (size_t)(d0 + dd) * S_ + s0 + ss8) = pk.v;
        }
    }
}

// ---------------------------------------------------------------- causal GQA flash attention v4
// Swapped-QK^T, 4 waves x 32 q-rows, KVBLK=64, mfma_32x32x16.
// v4: all LDS->reg fragment reads batched & hoisted (kA/kB up-front, vf
// prefetched under softmax); barrier #2 moved to just after the last LDS
// read so softmax+PV run in a barrier-free register-only region.
__global__ __launch_bounds__(256, 2) void attn_fwd3(const u16* __restrict__ qb,
                                                    const u16* __restrict__ kb,
                                                    const u16* __restrict__ vtb,
                                                    u16* __restrict__ attn) {
    __shared__ __align__(16) u16 Ks[2][64 * 128];   // 32KB (reused as O bounce)
    __shared__ __align__(16) u16 Vs[2][128 * 64];   // 32KB

    const int bh  = blockIdx.y;
    const int qt  = (bh < 16) ? (15 - (int)blockIdx.x) : (int)blockIdx.x;
    const int b   = bh >> 4, hq = bh & 15, hkv = hq >> 2;
    const int tid = threadIdx.x;
    const int wave = tid >> 6, lane = tid & 63;
    const int l31 = lane & 31, hi = lane >> 5;
    const int swz = (l31 & 7) << 4;

    const u16* Q  = qb  + (size_t)(b * HQ_  + hq ) * S_ * D_;
    const u16* Kp = kb  + (size_t)(b * HKV_ + hkv) * S_ * D_;
    const u16* Vt = vtb + (size_t)(b * HKV_ + hkv) * D_ * S_;
    const int q0w = qt * 128 + wave * 32;
    const int qg  = q0w + l31;            // this lane's q row

    int kSrc[4], vSrc[4], cLds[4];
    #pragma unroll
    for (int p = 0; p < 4; p++) {
        int c = tid + p * 256;
        int kr = c >> 4, kc = ((c & 15) * 16) ^ ((kr & 7) << 4);
        kSrc[p] = kr * D_ + (kc >> 1);
        int vr = c >> 3, vc = ((c & 7) * 16) ^ ((vr & 7) << 4);
        vSrc[p] = vr * S_ + (vc >> 1);
        cLds[p] = c * 16;
    }

    auto STAGE = [&](int buf, int kv0s) {
        const u16* kbase = Kp + (size_t)kv0s * D_;
        const u16* vbase = Vt + kv0s;
        #pragma unroll
        for (int p = 0; p < 4; p++)
            __builtin_amdgcn_global_load_lds(
                (const __attribute__((address_space(1))) void*)(kbase + kSrc[p]),
                (__attribute__((address_space(3))) void*)((char*)Ks[buf] + cLds[p]), 16, 0, 0);
        #pragma unroll
        for (int p = 0; p < 4; p++)
            __builtin_amdgcn_global_load_lds(
                (const __attribute__((address_space(1))) void*)(vbase + vSrc[p]),
                (__attribute__((address_space(3))) void*)((char*)Vs[buf] + cLds[p]), 16, 0, 0);
    };

    bf16x8 qf[8];
    #pragma unroll
    for (int ds = 0; ds < 8; ds++)
        qf[ds] = *(const bf16x8*)(Q + (size_t)qg * D_ + ds * 16 + hi * 8);

    float m_run = -1e30f, l_run = 0.f;
    f32x16 oacc[4] = {};

    const int nkt = 2 * qt + 2;
    STAGE(0, 0);

    for (int kt = 0; kt < nkt; kt++) {
        const int cur = kt & 1;
        const int kv0 = kt * 64;
        if (kt + 1 < nkt) {
            STAGE(cur ^ 1, kv0 + 64);
            asm volatile("s_waitcnt vmcnt(8)" ::: "memory");
        } else {
            asm volatile("s_waitcnt vmcnt(0)" ::: "memory");
        }
        __builtin_amdgcn_s_barrier();

        // ---- batch all K-fragment reads up-front (hides LDS latency)
        const char* ksb = (const char*)Ks[cur];
        const char* vsb = (const char*)Vs[cur];
        const char* rb0 = ksb + l31 * 256;
        const char* rb1 = rb0 + 32 * 256;
        bf16x8 kA[8], kB[8];
        #pragma unroll
        for (int ds = 0; ds < 8; ds++) kA[ds] = *(const bf16x8*)(rb0 + ((ds * 32 + hi * 16) ^ swz));
        #pragma unroll
        for (int ds = 0; ds < 8; ds++) kB[ds] = *(const bf16x8*)(rb1 + ((ds * 32 + hi * 16) ^ swz));

        // ---- QK^T swapped: S[kv][q], q = l31
        f32x16 sc[2] = {};
        __builtin_amdgcn_s_setprio(1);
        #pragma unroll
        for (int ds = 0; ds < 8; ds++)
            sc[0] = __builtin_amdgcn_mfma_f32_32x32x16_bf16(kA[ds], qf[ds], sc[0], 0, 0, 0);
        #pragma unroll
        for (int ds = 0; ds < 8; ds++)
            sc[1] = __builtin_amdgcn_mfma_f32_32x32x16_bf16(kB[ds], qf[ds], sc[1], 0, 0, 0);
        __builtin_amdgcn_s_setprio(0);

        // ---- prefetch all V fragments (latency hides under softmax)
        bf16x8 vf[4][4];
        #pragma unroll
        for (int ks = 0; ks < 4; ks++)
            #pragma unroll
            for (int d4 = 0; d4 < 4; d4++)
                vf[ks][d4] = *(const bf16x8*)(vsb + (d4 * 32 + l31) * 128
                                                  + ((ks * 32 + hi * 16) ^ swz));
        __builtin_amdgcn_s_barrier();   // all LDS reads of buf[cur] issued/done

        // ---- mask (diagonal tiles only)
        if (kv0 + 63 > q0w) {
            #pragma unroll
            for (int blk = 0; blk < 2; blk++)
                #pragma unroll
                for (int r = 0; r < 16; r++) {
                    int kvg = kv0 + blk * 32 + (r & 3) + 8 * (r >> 2) + 4 * hi;
                    if (kvg > qg) sc[blk][r] = -1e30f;
                }
        }

        // ---- in-lane row max + cross-half combine
        float t16[16];
        #pragma unroll
        for (int r = 0; r < 16; r++) t16[r] = fmaxf(sc[0][r], sc[1][r]);
        #pragma unroll
        for (int r = 0; r < 8; r++) t16[r] = fmaxf(t16[r], t16[r + 8]);
        #pragma unroll
        for (int r = 0; r < 4; r++) t16[r] = fmaxf(t16[r], t16[r + 4]);
        float mt = fmaxf(fmaxf(t16[0], t16[1]), fmaxf(t16[2], t16[3]));
        mt = fmaxf(mt, __shfl_xor(mt, 32));

        // ---- defer-max (T13)
        bool noDefer = !__all(mt <= m_run + 8.0f);
        float mnew = m_run;
        if (noDefer) {
            mnew = fmaxf(m_run, mt);
            float alpha = __builtin_amdgcn_exp2f(m_run - mnew);
            l_run *= alpha;
            #pragma unroll
            for (int d4 = 0; d4 < 4; d4++)
                #pragma unroll
                for (int r = 0; r < 16; r++) oacc[d4][r] *= alpha;
            m_run = mnew;
        }

        // ---- p = exp2(s - m), pack kv-consecutive pairs
        float la = 0.f;
        u32 pk0[8], pk1[8];
        #pragma unroll
        for (int g = 0; g < 4; g++)
            #pragma unroll
            for (int e = 0; e < 2; e++) {
                float a0 = __builtin_amdgcn_exp2f(sc[0][g * 4 + 2 * e]     - mnew);
                float b0 = __builtin_amdgcn_exp2f(sc[0][g * 4 + 2 * e + 1] - mnew);
                float a1 = __builtin_amdgcn_exp2f(sc[1][g * 4 + 2 * e]     - mnew);
                float b1 = __builtin_amdgcn_exp2f(sc[1][g * 4 + 2 * e + 1] - mnew);
                la += (a0 + b0) + (a1 + b1);
                pk0[g * 2 + e] = (u32)f2b(a0) | ((u32)f2b(b0) << 16);
                pk1[g * 2 + e] = (u32)f2b(a1) | ((u32)f2b(b1) << 16);
            }
        la += __shfl_xor(la, 32);
        l_run += la;

        u32 qk0[8], qk1[8];
        #pragma unroll
        for (int i = 0; i < 8; i++) {
            qk0[i] = __shfl_xor(pk0[i], 32);
            qk1[i] = __shfl_xor(pk1[i], 32);
        }

        // ---- PV: oacc[d4] += V^T(32x16) * P(16x32), all operands in-register
        #pragma unroll
        for (int ks = 0; ks < 4; ks++) {
            const int i0 = (ks & 1) * 4;
            union { u32 w[4]; bf16x8 v; } pfv;
            if (ks & 2) {
                pfv.w[0] = hi ? qk1[i0 + 2] : pk1[i0 + 0];
                pfv.w[1] = hi ? qk1[i0 + 3] : pk1[i0 + 1];
                pfv.w[2] = hi ? pk1[i0 + 2] : qk1[i0 + 0];
                pfv.w[3] = hi ? pk1[i0 + 3] : qk1[i0 + 1];
            } else {
                pfv.w[0] = hi ? qk0[i0 + 2] : pk0[i0 + 0];
                pfv.w[1] = hi ? qk0[i0 + 3] : pk0[i0 + 1];
                pfv.w[2] = hi ? pk0[i0 + 2] : qk0[i0 + 0];
                pfv.w[3] = hi ? pk0[i0 + 3] : qk0[i0 + 1];
            }
            __builtin_amdgcn_s_setprio(1);
            #pragma unroll
            for (int d4 = 0; d4 < 4; d4++)
                oacc[d4] = __builtin_amdgcn_mfma_f32_32x32x16_bf16(vf[ks][d4], pfv.v, oacc[d4], 0, 0, 0);
            __builtin_amdgcn_s_setprio(0);
        }
    }

    // ---- epilogue: normalize; bounce through (dead) Ks for coalesced stores
    const float inv = 1.0f / l_run;
    u16* sl = (u16*)Ks + wave * (32 * 128);
    #pragma unroll
    for (int d4 = 0; d4 < 4; d4++)
        #pragma unroll
        for (int rp = 0; rp < 8; rp++) {
            int dbyte = d4 * 64 + 16 * (rp >> 1) + 8 * hi + 4 * (rp & 1);
            u32 w = (u32)f2b(oacc[d4][rp * 2] * inv)
                  | ((u32)f2b(oacc[d4][rp * 2 + 1] * inv) << 16);
            *(u32*)((char*)sl + l31 * 256 + (dbyte ^ swz)) = w;
        }
    #pragma unroll
    for (int j = 0; j < 8; j++) {
        int c = lane + j * 64;
        int qL = c >> 4, dc = c & 15;
        uint4 v = *(uint4*)((char*)sl + qL * 256 + ((dc * 16) ^ ((qL & 7) << 4)));
        int qrow = qt * 128 + wave * 32 + qL;
        *(uint4*)(attn + (size_t)(b * S_ + qrow) * (HQ_ * D_) + hq * D_ + dc * 8) = v;
    }
}

// ---------------------------------------------------------------- launcher
extern "C" void kernel_launch(void* const* d_in, const int* in_sizes, int n_in,
                              void* d_out, int out_size, void* d_ws, size_t ws_size,
                              hipStream_t stream) {
    const float* hidden = (const float*)d_in[0];
    const float* cosb   = (const float*)d_in[1];
    const float* sinb   = (const float*)d_in[2];
    const float* qkvw   = (const float*)d_in[3];
    const float* nw     = (const float*)d_in[4];
    const float* ow     = (const float*)d_in[5];
    float* out = (float*)d_out;

    const size_t M  = (size_t)B_ * S_;             // 4096
    char* ws = (char*)d_ws;
    size_t off = 0;
    u16*   hb    = (u16*)(ws + off); off += M * HID * 2;                     // 16 MB (reused as attn)
    u16*   wqkvb = (u16*)(ws + off); off += (size_t)NQKV * HID * 2;          // 12 MB
    u16*   wob   = (u16*)(ws + off); off += (size_t)HID * (HQ_ * D_) * 2;    // 8 MB
    float* qkv   = (float*)(ws + off); off += M * NQKV * 4;                  // 48 MB
    u16*   qb2   = (u16*)(ws + off); off += (size_t)B_ * HQ_  * S_ * D_ * 2; // 16 MB
    u16*   kb2   = (u16*)(ws + off); off += (size_t)B_ * HKV_ * S_ * D_ * 2; // 4 MB
    u16*   vb2   = (u16*)(ws + off); off += (size_t)B_ * HKV_ * S_ * D_ * 2; // 4 MB
    u16*   vtb   = (u16*)(ws + off); off += (size_t)B_ * HKV_ * S_ * D_ * 2; // 4 MB
    u16*   attn  = hb;

    {
        int n4 = (int)(M * HID / 4);
        cvt_f32_bf16<<<(n4 + 255) / 256, 256, 0, stream>>>(hidden, hb, n4);
    }
    {
        int n4 = NQKV * HID / 4;
        cvt_f32_bf16<<<(n4 + 255) / 256, 256, 0, stream>>>(qkvw, wqkvb, n4);
    }
    {
        int n4 = HID * (HQ_ * D_) / 4;
        cvt_f32_bf16<<<(n4 + 255) / 256, 256, 0, stream>>>(ow, wob, n4);
    }

    const int smemSz = 131072;
    hipFuncSetAttribute(reinterpret_cast<const void*>(gemm256_bt),
                        hipFuncAttributeMaxDynamicSharedMemorySize, smemSz);

    gemm256_bt<<<dim3(M / 256, NQKV / 256), 512, smemSz, stream>>>(hb, wqkvb, qkv,
                                                                   (int)M, NQKV, HID);

    rope_norm_split<<<(int)M, 256, 0, stream>>>(qkv, cosb, sinb, nw, qb2, kb2, vb2);

    transpose_v<<<dim3(S_ / 64, D_ / 64, B_ * HKV_), 256, 0, stream>>>(vb2, vtb);

    attn_fwd3<<<dim3(16, B_ * HQ_), 256, 0, stream>>>(qb2, kb2, vtb, attn);

    gemm256_bt<<<dim3(M / 256, HID / 256), 512, smemSz, stream>>>(attn, wob, out,
                                                                  (int)M, HID, HQ_ * D_);
}